// Round 1
// baseline (860.120 us; speedup 1.0000x reference)
//
#include <hip/hip_runtime.h>

// One 64-lane wave per edge. Each lane owns 8 float4 chunks of the 2048-dim
// row (chunk j*64+lane) -> fully coalesced 16B/lane loads. rel is preloaded
// into 32 VGPRs per lane and reused across the wave's grid-stride edges.
__global__ __launch_bounds__(256) void edge_score_kernel(
    const float4* __restrict__ xs,   // head matrix, row-major, D=2048 (512 float4)
    const float4* __restrict__ xd,   // tail matrix
    const float4* __restrict__ rel,  // 512 float4
    const int* __restrict__ src,
    const int* __restrict__ dst,
    float* __restrict__ out,
    int E)
{
    const int lane = threadIdx.x & 63;
    const int waves_per_block = blockDim.x >> 6;
    int wid = blockIdx.x * waves_per_block + (threadIdx.x >> 6);
    const int nwaves = gridDim.x * waves_per_block;

    // preload this lane's rel chunk (8 float4 = 32 VGPRs)
    float4 r[8];
#pragma unroll
    for (int j = 0; j < 8; ++j) r[j] = rel[j * 64 + lane];

    for (int e = wid; e < E; e += nwaves) {
        const int s = src[e];
        const int d = dst[e];
        const float4* __restrict__ hp = xs + (size_t)s * 512;
        const float4* __restrict__ tp = xd + (size_t)d * 512;

        float acc = 0.f;
#pragma unroll
        for (int j = 0; j < 8; ++j) {
            float4 h = hp[j * 64 + lane];
            float4 t = tp[j * 64 + lane];
            acc = fmaf(h.x * r[j].x, t.x, acc);
            acc = fmaf(h.y * r[j].y, t.y, acc);
            acc = fmaf(h.z * r[j].z, t.z, acc);
            acc = fmaf(h.w * r[j].w, t.w, acc);
        }

        // 64-lane butterfly reduction
#pragma unroll
        for (int off = 32; off; off >>= 1)
            acc += __shfl_down(acc, off, 64);

        if (lane == 0) {
            out[e] = fminf(fmaxf(acc, 0.f), 1.f);
        }
    }
}

extern "C" void kernel_launch(void* const* d_in, const int* in_sizes, int n_in,
                              void* d_out, int out_size, void* d_ws, size_t ws_size,
                              hipStream_t stream) {
    const float* x_drug    = (const float*)d_in[0];
    const float* x_protein = (const float*)d_in[1];
    const float* rel_ddi   = (const float*)d_in[2];
    const float* rel_dpi   = (const float*)d_in[3];
    const int* ddi_src = (const int*)d_in[4];
    const int* ddi_dst = (const int*)d_in[5];
    const int* dpi_src = (const int*)d_in[6];
    const int* dpi_dst = (const int*)d_in[7];
    const int* ppi_src = (const int*)d_in[8];
    const int* ppi_dst = (const int*)d_in[9];

    const int E = in_sizes[4];           // 100000 edges per relation
    float* out = (float*)d_out;          // [score_ddi | score_dpi | score_ppi]

    const dim3 block(256);
    const int blocks = 2048;             // 8192 waves, grid-stride over E

    // DDI: drug -> drug, rel_ddi
    edge_score_kernel<<<blocks, block, 0, stream>>>(
        (const float4*)x_drug, (const float4*)x_drug, (const float4*)rel_ddi,
        ddi_src, ddi_dst, out, E);

    // DPI: drug -> protein, rel_dpi
    edge_score_kernel<<<blocks, block, 0, stream>>>(
        (const float4*)x_drug, (const float4*)x_protein, (const float4*)rel_dpi,
        dpi_src, dpi_dst, out + E, E);

    // PPI: protein -> protein, rel_dpi (faithful to reference quirk)
    edge_score_kernel<<<blocks, block, 0, stream>>>(
        (const float4*)x_protein, (const float4*)x_protein, (const float4*)rel_dpi,
        ppi_src, ppi_dst, out + 2 * E, E);
}

// Round 2
// 857.178 us; speedup vs baseline: 1.0034x; 1.0034x over previous
//
#include <hip/hip_runtime.h>

#define D4 512  // 2048 floats = 512 float4 per row

// One kernel for all three relations (3E edges). One 64-lane wave per edge,
// 2 edges in flight per wave iteration (ILP-2) -> 32 outstanding 16B loads.
// Both rel vectors staged in LDS (16 KB) to keep VGPR pressure low.
__global__ __launch_bounds__(256) void edge_score_all(
    const float4* __restrict__ xdrug,
    const float4* __restrict__ xprot,
    const float4* __restrict__ rddi,
    const float4* __restrict__ rdpi,
    const int* __restrict__ ddi_src, const int* __restrict__ ddi_dst,
    const int* __restrict__ dpi_src, const int* __restrict__ dpi_dst,
    const int* __restrict__ ppi_src, const int* __restrict__ ppi_dst,
    float* __restrict__ out, int E)
{
    __shared__ float4 srel[2][D4];
    for (int i = threadIdx.x; i < D4; i += blockDim.x) {
        srel[0][i] = rddi[i];
        srel[1][i] = rdpi[i];
    }
    __syncthreads();

    const int lane = threadIdx.x & 63;
    const int wpb  = blockDim.x >> 6;
    const int wid  = blockIdx.x * wpb + (threadIdx.x >> 6);
    const int nw   = gridDim.x * wpb;
    const int total = 3 * E;

    for (int e0 = wid; e0 < total; e0 += 2 * nw) {
        const int e1 = e0 + nw;
        const bool live1 = (e1 < total);
        const int e1c = live1 ? e1 : e0;   // clamp: compute garbage, skip store

        // resolve edge 0
        const float4 *hp0, *tp0;
        int sel0;
        if (e0 < E)            { hp0 = xdrug + (size_t)ddi_src[e0] * D4;
                                 tp0 = xdrug + (size_t)ddi_dst[e0] * D4; sel0 = 0; }
        else if (e0 < 2 * E)   { int k = e0 - E;
                                 hp0 = xdrug + (size_t)dpi_src[k] * D4;
                                 tp0 = xprot + (size_t)dpi_dst[k] * D4; sel0 = 1; }
        else                   { int k = e0 - 2 * E;
                                 hp0 = xprot + (size_t)ppi_src[k] * D4;
                                 tp0 = xprot + (size_t)ppi_dst[k] * D4; sel0 = 1; }

        // resolve edge 1
        const float4 *hp1, *tp1;
        int sel1;
        if (e1c < E)           { hp1 = xdrug + (size_t)ddi_src[e1c] * D4;
                                 tp1 = xdrug + (size_t)ddi_dst[e1c] * D4; sel1 = 0; }
        else if (e1c < 2 * E)  { int k = e1c - E;
                                 hp1 = xdrug + (size_t)dpi_src[k] * D4;
                                 tp1 = xprot + (size_t)dpi_dst[k] * D4; sel1 = 1; }
        else                   { int k = e1c - 2 * E;
                                 hp1 = xprot + (size_t)ppi_src[k] * D4;
                                 tp1 = xprot + (size_t)ppi_dst[k] * D4; sel1 = 1; }

        float acc0 = 0.f, acc1 = 0.f;
#pragma unroll
        for (int j = 0; j < 8; ++j) {
            const int idx = j * 64 + lane;
            float4 h0 = hp0[idx];
            float4 t0 = tp0[idx];
            float4 h1 = hp1[idx];
            float4 t1 = tp1[idx];
            float4 r0 = srel[sel0][idx];
            float4 r1 = srel[sel1][idx];
            acc0 = fmaf(h0.x * r0.x, t0.x, acc0);
            acc0 = fmaf(h0.y * r0.y, t0.y, acc0);
            acc0 = fmaf(h0.z * r0.z, t0.z, acc0);
            acc0 = fmaf(h0.w * r0.w, t0.w, acc0);
            acc1 = fmaf(h1.x * r1.x, t1.x, acc1);
            acc1 = fmaf(h1.y * r1.y, t1.y, acc1);
            acc1 = fmaf(h1.z * r1.z, t1.z, acc1);
            acc1 = fmaf(h1.w * r1.w, t1.w, acc1);
        }

#pragma unroll
        for (int off = 32; off; off >>= 1) {
            acc0 += __shfl_down(acc0, off, 64);
            acc1 += __shfl_down(acc1, off, 64);
        }

        if (lane == 0) {
            out[e0] = fminf(fmaxf(acc0, 0.f), 1.f);
            if (live1) out[e1] = fminf(fmaxf(acc1, 0.f), 1.f);
        }
    }
}

extern "C" void kernel_launch(void* const* d_in, const int* in_sizes, int n_in,
                              void* d_out, int out_size, void* d_ws, size_t ws_size,
                              hipStream_t stream) {
    const float* x_drug    = (const float*)d_in[0];
    const float* x_protein = (const float*)d_in[1];
    const float* rel_ddi   = (const float*)d_in[2];
    const float* rel_dpi   = (const float*)d_in[3];
    const int* ddi_src = (const int*)d_in[4];
    const int* ddi_dst = (const int*)d_in[5];
    const int* dpi_src = (const int*)d_in[6];
    const int* dpi_dst = (const int*)d_in[7];
    const int* ppi_src = (const int*)d_in[8];
    const int* ppi_dst = (const int*)d_in[9];

    const int E = in_sizes[4];          // 100000 edges per relation
    float* out = (float*)d_out;         // [score_ddi | score_dpi | score_ppi]

    const dim3 block(256);
    const int blocks = 2048;            // 8192 waves

    edge_score_all<<<blocks, block, 0, stream>>>(
        (const float4*)x_drug, (const float4*)x_protein,
        (const float4*)rel_ddi, (const float4*)rel_dpi,
        ddi_src, ddi_dst, dpi_src, dpi_dst, ppi_src, ppi_dst,
        out, E);
}

// Round 3
// 711.197 us; speedup vs baseline: 1.2094x; 1.2053x over previous
//
#include <hip/hip_runtime.h>

#define D4 512        // 2048 floats = 512 float4 per row
#define K_EDGES 16    // sorted edges per wave-chunk

// ---------- sort machinery (counting sort by src, per relation) ----------

__global__ void zero_ints(int* __restrict__ p, int n) {
    int i = blockIdx.x * blockDim.x + threadIdx.x;
    if (i < n) p[i] = 0;
}

// cnt layout: [0,nd) rel0(ddi) | [nd,2nd) rel1(dpi) | [2nd,2nd+np) rel2(ppi)
__global__ void hist3(const int* __restrict__ s0, const int* __restrict__ s1,
                      const int* __restrict__ s2, int E,
                      int* __restrict__ cnt, int nd) {
    int i = blockIdx.x * blockDim.x + threadIdx.x;
    const int total = 3 * E;
    for (; i < total; i += gridDim.x * blockDim.x) {
        if (i < E)           atomicAdd(&cnt[s0[i]], 1);
        else if (i < 2 * E)  atomicAdd(&cnt[nd + s1[i - E]], 1);
        else                 atomicAdd(&cnt[2 * nd + s2[i - 2 * E]], 1);
    }
}

// block b scans relation b's bucket counts -> exclusive bases (within-relation)
__global__ void scan3(const int* __restrict__ cnt, int* __restrict__ base,
                      int nd, int np) {
    __shared__ int part[1024];
    const int b = blockIdx.x;
    const int off = (b == 0) ? 0 : (b == 1) ? nd : 2 * nd;
    const int N = (b == 2) ? np : nd;
    const int t = threadIdx.x;
    const int C = (N + blockDim.x - 1) / blockDim.x;
    const int lo = t * C, hi = min(lo + C, N);
    int s = 0;
    for (int i = lo; i < hi; ++i) s += cnt[off + i];
    part[t] = s;
    __syncthreads();
    if (t == 0) {
        int run = 0;
        for (int i = 0; i < (int)blockDim.x; ++i) { int tmp = part[i]; part[i] = run; run += tmp; }
    }
    __syncthreads();
    int run = part[t];
    for (int i = lo; i < hi; ++i) { base[off + i] = run; run += cnt[off + i]; }
}

// scatter edge ids into src-grouped order (destroys base as the cursor)
__global__ void scatter3(const int* __restrict__ s0, const int* __restrict__ s1,
                         const int* __restrict__ s2, int E,
                         int* __restrict__ base, int nd, int* __restrict__ sorted) {
    int i = blockIdx.x * blockDim.x + threadIdx.x;
    const int total = 3 * E;
    for (; i < total; i += gridDim.x * blockDim.x) {
        if (i < E)          { int p = atomicAdd(&base[s0[i]], 1);           sorted[p] = i; }
        else if (i < 2 * E) { int k = i - E;     int p = atomicAdd(&base[nd + s1[k]], 1);     sorted[E + p] = k; }
        else                { int k = i - 2 * E; int p = atomicAdd(&base[2 * nd + s2[k]], 1); sorted[2 * E + p] = k; }
    }
}

// ---------- scoring over src-sorted edges ----------
// One wave per chunk of K_EDGES sorted edges. head*rel cached in 32 VGPRs
// across same-src runs; only the 8KB tail row streams per edge.
__global__ __launch_bounds__(256) void score_sorted(
    const float4* __restrict__ xdrug, const float4* __restrict__ xprot,
    const float4* __restrict__ rddi,  const float4* __restrict__ rdpi,
    const int* __restrict__ ddi_src, const int* __restrict__ ddi_dst,
    const int* __restrict__ dpi_src, const int* __restrict__ dpi_dst,
    const int* __restrict__ ppi_src, const int* __restrict__ ppi_dst,
    const int* __restrict__ sorted, float* __restrict__ out, int E)
{
    const int lane = threadIdx.x & 63;
    const int wpb = blockDim.x >> 6;
    int wid = blockIdx.x * wpb + (threadIdx.x >> 6);
    const int nw = gridDim.x * wpb;
    const int cpr = (E + K_EDGES - 1) / K_EDGES;   // chunks per relation
    const int total_chunks = 3 * cpr;

    for (int c = wid; c < total_chunks; c += nw) {
        const int r = c / cpr;
        const int ci = c - r * cpr;
        const int e_lo = ci * K_EDGES;
        const int e_hi = min(e_lo + K_EDGES, E);

        const float4 *xs, *xd, *rel;
        const int *srcA, *dstA, *sl;
        float* o;
        if (r == 0)      { xs = xdrug; xd = xdrug; rel = rddi; srcA = ddi_src; dstA = ddi_dst; sl = sorted;         o = out; }
        else if (r == 1) { xs = xdrug; xd = xprot; rel = rdpi; srcA = dpi_src; dstA = dpi_dst; sl = sorted + E;     o = out + E; }
        else             { xs = xprot; xd = xprot; rel = rdpi; srcA = ppi_src; dstA = ppi_dst; sl = sorted + 2 * E; o = out + 2 * E; }

        float4 rr[8];
#pragma unroll
        for (int j = 0; j < 8; ++j) rr[j] = rel[j * 64 + lane];

        int cur_src = -1;
        float4 hr[8];
        for (int i = e_lo; i < e_hi; ++i) {
            const int e = sl[i];
            const int s = srcA[e];
            if (s != cur_src) {       // wave-uniform branch
                cur_src = s;
                const float4* __restrict__ hp = xs + (size_t)s * D4;
#pragma unroll
                for (int j = 0; j < 8; ++j) {
                    float4 h = hp[j * 64 + lane];
                    hr[j].x = h.x * rr[j].x;
                    hr[j].y = h.y * rr[j].y;
                    hr[j].z = h.z * rr[j].z;
                    hr[j].w = h.w * rr[j].w;
                }
            }
            const int d = dstA[e];
            const float4* __restrict__ tp = xd + (size_t)d * D4;
            float acc = 0.f;
#pragma unroll
            for (int j = 0; j < 8; ++j) {
                float4 t = tp[j * 64 + lane];
                acc = fmaf(hr[j].x, t.x, acc);
                acc = fmaf(hr[j].y, t.y, acc);
                acc = fmaf(hr[j].z, t.z, acc);
                acc = fmaf(hr[j].w, t.w, acc);
            }
#pragma unroll
            for (int off = 32; off; off >>= 1) acc += __shfl_down(acc, off, 64);
            if (lane == 0) o[e] = fminf(fmaxf(acc, 0.f), 1.f);
        }
    }
}

// ---------- fallback (round-2 direct kernel) if ws too small ----------
__global__ __launch_bounds__(256) void edge_score_all(
    const float4* __restrict__ xdrug, const float4* __restrict__ xprot,
    const float4* __restrict__ rddi,  const float4* __restrict__ rdpi,
    const int* __restrict__ ddi_src, const int* __restrict__ ddi_dst,
    const int* __restrict__ dpi_src, const int* __restrict__ dpi_dst,
    const int* __restrict__ ppi_src, const int* __restrict__ ppi_dst,
    float* __restrict__ out, int E)
{
    __shared__ float4 srel[2][D4];
    for (int i = threadIdx.x; i < D4; i += blockDim.x) {
        srel[0][i] = rddi[i];
        srel[1][i] = rdpi[i];
    }
    __syncthreads();
    const int lane = threadIdx.x & 63;
    const int wpb = blockDim.x >> 6;
    int wid = blockIdx.x * wpb + (threadIdx.x >> 6);
    const int nw = gridDim.x * wpb;
    const int total = 3 * E;
    for (int e = wid; e < total; e += nw) {
        const float4 *hp, *tp;
        int sel;
        if (e < E)          { hp = xdrug + (size_t)ddi_src[e] * D4; tp = xdrug + (size_t)ddi_dst[e] * D4; sel = 0; }
        else if (e < 2 * E) { int k = e - E;     hp = xdrug + (size_t)dpi_src[k] * D4; tp = xprot + (size_t)dpi_dst[k] * D4; sel = 1; }
        else                { int k = e - 2 * E; hp = xprot + (size_t)ppi_src[k] * D4; tp = xprot + (size_t)ppi_dst[k] * D4; sel = 1; }
        float acc = 0.f;
#pragma unroll
        for (int j = 0; j < 8; ++j) {
            const int idx = j * 64 + lane;
            float4 h = hp[idx], t = tp[idx], r = srel[sel][idx];
            acc = fmaf(h.x * r.x, t.x, acc);
            acc = fmaf(h.y * r.y, t.y, acc);
            acc = fmaf(h.z * r.z, t.z, acc);
            acc = fmaf(h.w * r.w, t.w, acc);
        }
#pragma unroll
        for (int off = 32; off; off >>= 1) acc += __shfl_down(acc, off, 64);
        if (lane == 0) out[e] = fminf(fmaxf(acc, 0.f), 1.f);
    }
}

extern "C" void kernel_launch(void* const* d_in, const int* in_sizes, int n_in,
                              void* d_out, int out_size, void* d_ws, size_t ws_size,
                              hipStream_t stream) {
    const float* x_drug    = (const float*)d_in[0];
    const float* x_protein = (const float*)d_in[1];
    const float* rel_ddi   = (const float*)d_in[2];
    const float* rel_dpi   = (const float*)d_in[3];
    const int* ddi_src = (const int*)d_in[4];
    const int* ddi_dst = (const int*)d_in[5];
    const int* dpi_src = (const int*)d_in[6];
    const int* dpi_dst = (const int*)d_in[7];
    const int* ppi_src = (const int*)d_in[8];
    const int* ppi_dst = (const int*)d_in[9];

    const int D  = in_sizes[2];              // 2048
    const int nd = in_sizes[0] / D;          // N_DRUG
    const int np = in_sizes[1] / D;          // N_PROT
    const int E  = in_sizes[4];              // edges per relation
    float* out = (float*)d_out;

    const int CB = 2 * nd + np;              // bucket count (all relations)
    const size_t need = (size_t)(2 * CB + 3 * E) * sizeof(int);

    if (ws_size < need) {                    // fallback: direct kernel
        edge_score_all<<<2048, 256, 0, stream>>>(
            (const float4*)x_drug, (const float4*)x_protein,
            (const float4*)rel_ddi, (const float4*)rel_dpi,
            ddi_src, ddi_dst, dpi_src, dpi_dst, ppi_src, ppi_dst, out, E);
        return;
    }

    int* cnt    = (int*)d_ws;                // CB ints
    int* base   = cnt + CB;                  // CB ints (becomes cursor)
    int* sorted = base + CB;                 // 3E ints

    zero_ints<<<(CB + 255) / 256, 256, 0, stream>>>(cnt, CB);
    hist3<<<1024, 256, 0, stream>>>(ddi_src, dpi_src, ppi_src, E, cnt, nd);
    scan3<<<3, 1024, 0, stream>>>(cnt, base, nd, np);
    scatter3<<<1024, 256, 0, stream>>>(ddi_src, dpi_src, ppi_src, E, base, nd, sorted);

    const int cpr = (E + K_EDGES - 1) / K_EDGES;
    const int total_chunks = 3 * cpr;
    const int waves_per_block = 4;           // 256 threads
    const int blocks = (total_chunks + waves_per_block - 1) / waves_per_block;

    score_sorted<<<blocks, 256, 0, stream>>>(
        (const float4*)x_drug, (const float4*)x_protein,
        (const float4*)rel_ddi, (const float4*)rel_dpi,
        ddi_src, ddi_dst, dpi_src, dpi_dst, ppi_src, ppi_dst,
        sorted, out, E);
}